// Round 11
// baseline (758.804 us; speedup 1.0000x reference)
//
#include <hip/hip_runtime.h>
#include <stdint.h>

#define BATCH 128
#define SEQL  512
#define FDIM  768
#define CTAGS 52
#define START_IDX 50
#define STOP_IDX  51
#define NEG_INF (-3.0e38f)

// ---------------------------------------------------------------------------
// K-1: zero the ready flags (every launch -> graph-replay safe).
// ---------------------------------------------------------------------------
__global__ __launch_bounds__(256) void init_flags(int* __restrict__ ready)
{
    ready[blockIdx.x * 256 + threadIdx.x] = 0;
}

// ---------------------------------------------------------------------------
// K0: transpose W [52][768] -> WT [768][52]. Tiny, runs once.
// ---------------------------------------------------------------------------
__global__ __launch_bounds__(256) void wtrans(
    const float* __restrict__ W, float* __restrict__ WT)
{
    int idx = blockIdx.x * 256 + threadIdx.x;
    if (idx < FDIM * CTAGS) {
        int k = idx / CTAGS;
        int c = idx - k * CTAGS;
        WT[idx] = W[(size_t)c * FDIM + k];
    }
}

// ---------------------------------------------------------------------------
// K1 (mega): heterogeneous blocks.
//   blocks 0..127     : R7's proven serial scan (1 wave; LDS state broadcast,
//                       zero barriers), waiting on per-(batch,pair) ready
//                       flags before staging each 32-step chunk.
//   blocks 128..1151  : R7's proven gemm4 tile (64 rows, W scalar path,
//                       F via padded LDS, double-buffered), pair-major order:
//                       block 128 + p*128 + b computes batch b rows
//                       [64p, 64p+64), then releases flag[b*8+p].
// Union LDS 17408 B -> 8 blocks/CU -> all 1152 blocks co-resident: no
// deadlock regardless of dispatch order.
// ---------------------------------------------------------------------------
#define BK32 32
#define LPAD 33
#define CHUNK 32
#define CQ   (CHUNK * CTAGS / 4)   // 416 float4 per chunk
#define NCH32 (SEQL / CHUNK)       // 16 chunks
#define SMEM_BYTES 17408

__device__ __forceinline__ void wait_flag(int* f)
{
    while (__hip_atomic_load(f, __ATOMIC_RELAXED, __HIP_MEMORY_SCOPE_AGENT) == 0)
        __builtin_amdgcn_s_sleep(2);
    __threadfence();   // acquire: order flag read before emit reads
}

__global__ __launch_bounds__(256) void mega(
    const float* __restrict__ F, const float* __restrict__ WT,
    const float* __restrict__ bias, const int* __restrict__ masks,
    const float* __restrict__ T, float* __restrict__ emit,  // aliased s_hist
    float* __restrict__ out, int* __restrict__ btag, int* __restrict__ ready)
{
    __shared__ __align__(16) char smem[SMEM_BYTES];
    const int bid = blockIdx.x;

    if (bid < BATCH) {
        // ==================== SCAN BLOCK (wave 0 only) ====================
        if ((threadIdx.x >> 6) != 0) return;
        const int b  = bid;
        const int to = threadIdx.x & 63;
        const int toc = (to < CTAGS) ? to : (CTAGS - 1);

        float* ebuf0 = (float*)smem;                    // [CHUNK*CTAGS]
        float* ebuf1 = ebuf0 + CHUNK * CTAGS;
        int*   ml    = (int*)(smem + 13312);            // [SEQL]
        float* st    = (float*)(smem + 15360);          // [64]

        const float4* Tq = (const float4*)(T + (size_t)toc * CTAGS);
        const float4 tr0 = Tq[0],  tr1 = Tq[1],  tr2 = Tq[2],  tr3 = Tq[3];
        const float4 tr4 = Tq[4],  tr5 = Tq[5],  tr6 = Tq[6],  tr7 = Tq[7];
        const float4 tr8 = Tq[8],  tr9 = Tq[9],  tr10 = Tq[10], tr11 = Tq[11];
        const float4 tr12 = Tq[12];
        const float tstop = T[STOP_IDX * CTAGS + toc];

        const float*  eb  = emit  + (size_t)b * SEQL * CTAGS;
        const float4* ebq = (const float4*)eb;
        const int*    mb  = masks + (size_t)b * SEQL;
        float*        sb  = emit  + (size_t)b * SEQL * CTAGS;  // s_hist alias
        int*          rdy = ready + b * 8;

        // prologue: masks -> LDS ; wait pair 0 ; chunk 0 -> LDS ; state init
#pragma unroll
        for (int j = 0; j < 8; ++j) ml[to + 64 * j] = mb[to + 64 * j];

        wait_flag(&rdy[0]);
#pragma unroll
        for (int j = 0; j < 7; ++j) {
            int idx = to + 64 * j;
            if (idx < CQ) *(float4*)&ebuf0[idx * 4] = ebq[idx];
        }
        st[to] = (to == START_IDX) ? 0.f : -10000.f;

        float cur   = (to == START_IDX) ? 0.f : -10000.f;
        float e_cur = ebuf0[toc];
        int   m_cur = ml[0];
        int   cb    = 0;

        for (int c = 0; c < NCH32; ++c) {
            float4 p0, p1, p2, p3, p4, p5, p6;
            const int more = (c < NCH32 - 1);
            if (more) {
                wait_flag(&rdy[(c + 1) >> 1]);   // pair holding chunk c+1
                const float4* src = ebq + (size_t)(c + 1) * CQ;
                p0 = src[to];
                p1 = src[to + 64];
                p2 = src[to + 128];
                p3 = src[to + 192];
                p4 = src[to + 256];
                p5 = src[to + 320];
                if (to < CQ - 384) p6 = src[to + 384];
            }

            float* ebc = cb ? ebuf1 : ebuf0;
            for (int s = 0; s < CHUNK; ++s) {
                const int t = c * CHUNK + s;

                float e = (s < CHUNK - 1) ? ebc[(s + 1) * CTAGS + toc] : 0.f;
                int   m_nxt = (t + 1 < SEQL) ? ml[t + 1] : 0;

                if (to < CTAGS) sb[(size_t)t * CTAGS + to] = cur;

                const float4 s0q  = *(const float4*)&st[0];
                const float4 s1q  = *(const float4*)&st[4];
                const float4 s2q  = *(const float4*)&st[8];
                const float4 s3q  = *(const float4*)&st[12];
                const float4 s4q  = *(const float4*)&st[16];
                const float4 s5q  = *(const float4*)&st[20];
                const float4 s6q  = *(const float4*)&st[24];
                const float4 s7q  = *(const float4*)&st[28];
                const float4 s8q  = *(const float4*)&st[32];
                const float4 s9q  = *(const float4*)&st[36];
                const float4 s10q = *(const float4*)&st[40];
                const float4 s11q = *(const float4*)&st[44];
                const float4 s12q = *(const float4*)&st[48];

                float a[CTAGS];
#define ADQ(q, sq, trq)                                                      \
                a[4*q+0] = sq.x + trq.x;  a[4*q+1] = sq.y + trq.y;           \
                a[4*q+2] = sq.z + trq.z;  a[4*q+3] = sq.w + trq.w;
                ADQ(0, s0q, tr0)   ADQ(1, s1q, tr1)   ADQ(2, s2q, tr2)
                ADQ(3, s3q, tr3)   ADQ(4, s4q, tr4)   ADQ(5, s5q, tr5)
                ADQ(6, s6q, tr6)   ADQ(7, s7q, tr7)   ADQ(8, s8q, tr8)
                ADQ(9, s9q, tr9)   ADQ(10, s10q, tr10) ADQ(11, s11q, tr11)
                ADQ(12, s12q, tr12)
#undef ADQ

                float l1[17];
#pragma unroll
                for (int i = 0; i < 17; ++i)
                    l1[i] = fmaxf(fmaxf(a[3 * i], a[3 * i + 1]), a[3 * i + 2]);
                float l2[6];
#pragma unroll
                for (int i = 0; i < 5; ++i)
                    l2[i] = fmaxf(fmaxf(l1[3 * i], l1[3 * i + 1]), l1[3 * i + 2]);
                l2[5] = fmaxf(fmaxf(l1[15], l1[16]), a[51]);
                const float mx = fmaxf(fmaxf(fmaxf(l2[0], l2[1]), l2[2]),
                                       fmaxf(fmaxf(l2[3], l2[4]), l2[5]));

                cur = m_cur ? (mx + e_cur) : cur;

                if (to < CTAGS) st[to] = cur;

                e_cur = e;
                m_cur = m_nxt;
            }

            if (more) {
                float* nbuf = cb ? ebuf0 : ebuf1;
                *(float4*)&nbuf[to * 4]         = p0;
                *(float4*)&nbuf[(to + 64) * 4]  = p1;
                *(float4*)&nbuf[(to + 128) * 4] = p2;
                *(float4*)&nbuf[(to + 192) * 4] = p3;
                *(float4*)&nbuf[(to + 256) * 4] = p4;
                *(float4*)&nbuf[(to + 320) * 4] = p5;
                if (to < CQ - 384) *(float4*)&nbuf[(to + 384) * 4] = p6;
                e_cur = nbuf[toc];   // in-order LDS: writes complete first
            }
            cb ^= 1;
        }

        float v   = (to < CTAGS) ? (cur + tstop) : NEG_INF;
        int  bidx = to;
#pragma unroll
        for (int s = 1; s < 64; s <<= 1) {
            float ov = __shfl_xor(v, s);
            int   oi = __shfl_xor(bidx, s);
            if (ov > v || (ov == v && oi < bidx)) { v = ov; bidx = oi; }
        }
        if (to == 0) { out[b] = v; btag[b] = bidx; }

    } else {
        // ==================== GEMM BLOCK (4 waves) ========================
        const int g2   = bid - BATCH;
        const int p    = g2 >> 7;            // pair 0..7
        const int b    = g2 & 127;           // batch
        const int row0 = b * SEQL + p * 64;

        float* buf0 = (float*)smem;          // [64*LPAD]
        float* buf1 = buf0 + 64 * LPAD;

        const int tid  = threadIdx.x;
        const int lane = tid & 63;
        const int cg   = __builtin_amdgcn_readfirstlane(tid >> 6);
        const int c0   = cg * 13;

        const int r0 = tid >> 3;
        const int s0 = tid & 7;
        const float* g0 = F + (size_t)(row0 + r0) * FDIM + s0 * 4;
        const float* g1 = g0 + (size_t)32 * FDIM;
        const int i0 = r0 * LPAD + s0 * 4;
        const int i1 = (r0 + 32) * LPAD + s0 * 4;

        float acc[13];
#pragma unroll
        for (int c = 0; c < 13; ++c) acc[c] = bias[c0 + c];

        {
            float4 a0 = *(const float4*)g0;
            float4 a1 = *(const float4*)g1;
            buf0[i0 + 0] = a0.x; buf0[i0 + 1] = a0.y;
            buf0[i0 + 2] = a0.z; buf0[i0 + 3] = a0.w;
            buf0[i1 + 0] = a1.x; buf0[i1 + 1] = a1.y;
            buf0[i1 + 2] = a1.z; buf0[i1 + 3] = a1.w;
        }
        __syncthreads();

        int cur = 0;
        for (int t = 0; t < FDIM / BK32; ++t) {
            const int k0 = t * BK32;

            float4 b0, b1;
            if (t < FDIM / BK32 - 1) {
                b0 = *(const float4*)(g0 + k0 + BK32);
                b1 = *(const float4*)(g1 + k0 + BK32);
            }

            const float* fb = (cur ? buf1 : buf0) + lane * LPAD;
#pragma unroll
            for (int kk = 0; kk < BK32; kk += 4) {
                float f0 = fb[kk + 0], f1 = fb[kk + 1];
                float f2 = fb[kk + 2], f3 = fb[kk + 3];
                const float* w0 = WT + (size_t)(k0 + kk + 0) * CTAGS + c0;
                const float* w1 = WT + (size_t)(k0 + kk + 1) * CTAGS + c0;
                const float* w2 = WT + (size_t)(k0 + kk + 2) * CTAGS + c0;
                const float* w3 = WT + (size_t)(k0 + kk + 3) * CTAGS + c0;
#pragma unroll
                for (int c = 0; c < 13; ++c) {
                    acc[c] = fmaf(f0, w0[c], acc[c]);
                    acc[c] = fmaf(f1, w1[c], acc[c]);
                    acc[c] = fmaf(f2, w2[c], acc[c]);
                    acc[c] = fmaf(f3, w3[c], acc[c]);
                }
            }

            if (t < FDIM / BK32 - 1) {
                float* nb = cur ? buf0 : buf1;
                nb[i0 + 0] = b0.x; nb[i0 + 1] = b0.y;
                nb[i0 + 2] = b0.z; nb[i0 + 3] = b0.w;
                nb[i1 + 0] = b1.x; nb[i1 + 1] = b1.y;
                nb[i1 + 2] = b1.z; nb[i1 + 3] = b1.w;
            }
            __syncthreads();
            cur ^= 1;
        }

        float* eo = emit + (size_t)(row0 + lane) * CTAGS + c0;
#pragma unroll
        for (int c = 0; c < 13; ++c) eo[c] = acc[c];

        // publish: all stores agent-visible, then release the pair flag
        __threadfence();
        __syncthreads();
        if (tid == 0)
            __hip_atomic_store(&ready[b * 8 + p], 1, __ATOMIC_RELEASE,
                               __HIP_MEMORY_SCOPE_AGENT);
    }
}

// ---------------------------------------------------------------------------
// K3: backpointers, parallel over (b,t). (unchanged, known-good)
// ---------------------------------------------------------------------------
#define PPW 16

__global__ __launch_bounds__(256) void bp_compute(
    const float* __restrict__ s_hist, const float* __restrict__ T,
    unsigned char* __restrict__ bp)
{
    const int lane = threadIdx.x & 63;
    const int wv   = __builtin_amdgcn_readfirstlane(threadIdx.x >> 6);
    const int toc  = (lane < CTAGS) ? lane : (CTAGS - 1);
    const int w    = blockIdx.x * 4 + wv;

    float Trow[CTAGS];
#pragma unroll
    for (int f = 0; f < CTAGS; ++f) Trow[f] = T[toc * CTAGS + f];

    for (int i = 0; i < PPW; ++i) {
        const int p = w * PPW + i;            // p = b*SEQL + t
        const float* sp = s_hist + (size_t)p * CTAGS;

        float a[CTAGS];
#pragma unroll
        for (int q = 0; q < 13; ++q) {
            float4 sv = *(const float4*)(sp + q * 4);
            a[q * 4 + 0] = sv.x + Trow[q * 4 + 0];
            a[q * 4 + 1] = sv.y + Trow[q * 4 + 1];
            a[q * 4 + 2] = sv.z + Trow[q * 4 + 2];
            a[q * 4 + 3] = sv.w + Trow[q * 4 + 3];
        }

        float l1[17];
#pragma unroll
        for (int j = 0; j < 17; ++j)
            l1[j] = fmaxf(fmaxf(a[3 * j], a[3 * j + 1]), a[3 * j + 2]);
        float l2[6];
#pragma unroll
        for (int j = 0; j < 5; ++j)
            l2[j] = fmaxf(fmaxf(l1[3 * j], l1[3 * j + 1]), l1[3 * j + 2]);
        l2[5] = fmaxf(fmaxf(l1[15], l1[16]), a[51]);
        const float m = fmaxf(fmaxf(fmaxf(l2[0], l2[1]), l2[2]),
                              fmaxf(fmaxf(l2[3], l2[4]), l2[5]));

        int c1[18];
#pragma unroll
        for (int j = 0; j < 17; ++j) {
            int x = (a[3 * j]     == m) ? (3 * j)     : 63;
            int y = (a[3 * j + 1] == m) ? (3 * j + 1) : 63;
            int z = (a[3 * j + 2] == m) ? (3 * j + 2) : 63;
            c1[j] = min(min(x, y), z);
        }
        c1[17] = (a[51] == m) ? 51 : 63;
        int c2[6];
#pragma unroll
        for (int j = 0; j < 6; ++j)
            c2[j] = min(min(c1[3 * j], c1[3 * j + 1]), c1[3 * j + 2]);
        const int idx = min(min(min(c2[0], c2[1]), c2[2]),
                            min(min(c2[3], c2[4]), c2[5]));

        if (lane < CTAGS)
            bp[(size_t)p * CTAGS + lane] = (unsigned char)idx;
    }
}

// ---------------------------------------------------------------------------
// K4: backtrack (unchanged, known-good).
// ---------------------------------------------------------------------------
__global__ __launch_bounds__(64) void viterbi_bt(
    const unsigned char* __restrict__ bp, const int* __restrict__ masks,
    const int* __restrict__ btag, float* __restrict__ out)
{
    const int b   = blockIdx.x;
    const int tid = threadIdx.x;

    __shared__ __align__(16) unsigned char bpl[SEQL * CTAGS];
    __shared__ int ml[SEQL];
    __shared__ unsigned char pathb[SEQL];

    const uint4* src = (const uint4*)(bp + (size_t)b * SEQL * CTAGS);
    for (int i = tid; i < SEQL * CTAGS / 16; i += 64)
        ((uint4*)bpl)[i] = src[i];
    for (int i = tid; i < SEQL; i += 64) ml[i] = masks[(size_t)b * SEQL + i];
    __syncthreads();

    int c = btag[b];
    if (tid == 0) pathb[SEQL - 1] = (unsigned char)c;
    for (int i = SEQL - 2; i >= 0; --i) {
        int nxt = bpl[(i + 1) * CTAGS + c];
        c = ml[i] ? nxt : c;
        if (tid == 0) pathb[i] = (unsigned char)c;
    }
    __syncthreads();

    float* po = out + BATCH + (size_t)b * SEQL;
#pragma unroll
    for (int i = 0; i < 8; ++i)
        po[i * 64 + tid] = (float)pathb[i * 64 + tid];
}

// ---------------------------------------------------------------------------
extern "C" void kernel_launch(void* const* d_in, const int* in_sizes, int n_in,
                              void* d_out, int out_size, void* d_ws, size_t ws_size,
                              hipStream_t stream)
{
    const float* features = (const float*)d_in[0];
    const int*   masks    = (const int*)d_in[1];
    const float* W        = (const float*)d_in[2];
    const float* bias     = (const float*)d_in[3];
    const float* T        = (const float*)d_in[4];

    float* out = (float*)d_out;

    // ws: emit/s_hist (13.63 MB, aliased) | bp (3.41 MB) | btag | flags
    // WT (160 KB) aliases the bp region: read during mega, dead before
    // bp_compute overwrites it (stream-ordered).
    const size_t emit_bytes = (size_t)BATCH * SEQL * CTAGS * sizeof(float);
    const size_t bp_bytes   = (size_t)BATCH * SEQL * CTAGS;
    float*         emit   = (float*)d_ws;
    float*         s_hist = emit;
    unsigned char* bpws   = (unsigned char*)d_ws + emit_bytes;
    float*         WT     = (float*)bpws;
    int*           btag   = (int*)((unsigned char*)d_ws + emit_bytes + bp_bytes);
    int*           ready  = (int*)((unsigned char*)d_ws + emit_bytes + bp_bytes + 4096);

    init_flags<<<4, 256, 0, stream>>>(ready);
    wtrans<<<(FDIM * CTAGS + 255) / 256, 256, 0, stream>>>(W, WT);
    mega<<<BATCH + BATCH * 8, 256, 0, stream>>>(features, WT, bias, masks, T,
                                                emit, out, btag, ready);
    bp_compute<<<BATCH * SEQL / (4 * PPW), 256, 0, stream>>>(s_hist, T, bpws);
    viterbi_bt<<<BATCH, 64, 0, stream>>>(bpws, masks, btag, out);
}

// Round 12
// 328.673 us; speedup vs baseline: 2.3087x; 2.3087x over previous
//
#include <hip/hip_runtime.h>
#include <stdint.h>

#define BATCH 128
#define SEQL  512
#define FDIM  768
#define CTAGS 52
#define START_IDX 50
#define STOP_IDX  51
#define NEG_INF (-3.0e38f)

// ---------------------------------------------------------------------------
// K0: transpose W [52][768] -> WT [768][52]. Tiny, runs once.
// ---------------------------------------------------------------------------
__global__ __launch_bounds__(256) void wtrans(
    const float* __restrict__ W, float* __restrict__ WT)
{
    int idx = blockIdx.x * 256 + threadIdx.x;
    if (idx < FDIM * CTAGS) {
        int k = idx / CTAGS;
        int c = idx - k * CTAGS;
        WT[idx] = W[(size_t)c * FDIM + k];
    }
}

// ---------------------------------------------------------------------------
// K1: emission GEMM v6 — NO LDS, no barriers. lane = row; wave covers 64 rows
// x 13 cols (c0 = 13*wave). F streamed per-lane via global dwordx4 on the
// vmcnt pipe, prefetched one 16-k super-group ahead. W on the scalar s_load
// path (wave-uniform addresses) — the ONLY lgkmcnt user, so its waits are
// fine-grained. 4 waves/block read the same 64 F rows -> L1 serves the 4x
// reuse (working set ~4KB). Issue floor 33 us.
// ---------------------------------------------------------------------------
__global__ __launch_bounds__(256) void emit_gemm6(
    const float* __restrict__ F, const float* __restrict__ WT,
    const float* __restrict__ bias, float* __restrict__ emit)
{
    const int lane = threadIdx.x & 63;
    const int cg   = __builtin_amdgcn_readfirstlane(threadIdx.x >> 6);
    const int c0   = cg * 13;
    const int row  = blockIdx.x * 64 + lane;

    const float* fp = F + (size_t)row * FDIM;

    float acc[13];
#pragma unroll
    for (int c = 0; c < 13; ++c) acc[c] = bias[c0 + c];

    // 4-k sub-group: 13 uniform W floats per k row (s_load), 52 FMAs
#define SUB(fq, kbase)                                                       \
    {                                                                        \
        const float* w0 = WT + (size_t)((kbase) + 0) * CTAGS + c0;           \
        const float* w1 = WT + (size_t)((kbase) + 1) * CTAGS + c0;           \
        const float* w2 = WT + (size_t)((kbase) + 2) * CTAGS + c0;           \
        const float* w3 = WT + (size_t)((kbase) + 3) * CTAGS + c0;           \
        _Pragma("unroll")                                                    \
        for (int c = 0; c < 13; ++c) {                                       \
            acc[c] = fmaf(fq.x, w0[c], acc[c]);                              \
            acc[c] = fmaf(fq.y, w1[c], acc[c]);                              \
            acc[c] = fmaf(fq.z, w2[c], acc[c]);                              \
            acc[c] = fmaf(fq.w, w3[c], acc[c]);                              \
        }                                                                    \
    }

    // prologue: load first 16-k super-group
    float4 fA = *(const float4*)(fp + 0);
    float4 fB = *(const float4*)(fp + 4);
    float4 fC = *(const float4*)(fp + 8);
    float4 fD = *(const float4*)(fp + 12);

    for (int k0 = 0; k0 < FDIM; k0 += 16) {
        // prefetch next super-group (vmcnt pipe; consumed ~500 cyc later)
        float4 nA, nB, nC, nD;
        if (k0 + 16 < FDIM) {
            nA = *(const float4*)(fp + k0 + 16);
            nB = *(const float4*)(fp + k0 + 20);
            nC = *(const float4*)(fp + k0 + 24);
            nD = *(const float4*)(fp + k0 + 28);
        }

        SUB(fA, k0 + 0)
        SUB(fB, k0 + 4)
        SUB(fC, k0 + 8)
        SUB(fD, k0 + 12)

        fA = nA; fB = nB; fC = nC; fD = nD;
    }
#undef SUB

    float* eo = emit + (size_t)row * CTAGS + c0;
#pragma unroll
    for (int c = 0; c < 13; ++c) eo[c] = acc[c];
}

// ---------------------------------------------------------------------------
// K2: serial Viterbi scan (R7 champion, byte-identical logic).
// ---------------------------------------------------------------------------
#define CHUNK 32
#define CQ   (CHUNK * CTAGS / 4)   // float4s per chunk = 416

__global__ __launch_bounds__(64) void viterbi_scan(
    const float* __restrict__ emit, const int* __restrict__ masks,
    const float* __restrict__ T, float* __restrict__ s_hist,
    float* __restrict__ out, int* __restrict__ btag)
{
    const int b  = blockIdx.x;
    const int to = threadIdx.x;
    const int toc = (to < CTAGS) ? to : (CTAGS - 1);

    __shared__ float ebuf[2][CHUNK * CTAGS];     // 2 x 6656 B
    __shared__ int   ml[SEQL];                   // 2 KB
    __shared__ __align__(16) float st[64];       // state vector (52 used)

    const float4* Tq = (const float4*)(T + (size_t)toc * CTAGS);
    const float4 tr0 = Tq[0],  tr1 = Tq[1],  tr2 = Tq[2],  tr3 = Tq[3];
    const float4 tr4 = Tq[4],  tr5 = Tq[5],  tr6 = Tq[6],  tr7 = Tq[7];
    const float4 tr8 = Tq[8],  tr9 = Tq[9],  tr10 = Tq[10], tr11 = Tq[11];
    const float4 tr12 = Tq[12];
    const float tstop = T[STOP_IDX * CTAGS + toc];

    const float*  eb  = emit   + (size_t)b * SEQL * CTAGS;
    const float4* ebq = (const float4*)eb;
    const int*    mb  = masks  + (size_t)b * SEQL;
    float*        sb  = s_hist + (size_t)b * SEQL * CTAGS;

#pragma unroll
    for (int j = 0; j < 8; ++j) ml[to + 64 * j] = mb[to + 64 * j];
#pragma unroll
    for (int j = 0; j < 7; ++j) {
        int idx = to + 64 * j;
        if (idx < CQ) *(float4*)&ebuf[0][idx * 4] = ebq[idx];
    }
    st[to] = (to == START_IDX) ? 0.f : -10000.f;

    float cur   = (to == START_IDX) ? 0.f : -10000.f;
    float e_cur = ebuf[0][toc];
    int   m_cur = ml[0];
    int   cb    = 0;

    for (int c = 0; c < SEQL / CHUNK; ++c) {
        float4 p0, p1, p2, p3, p4, p5, p6;
        const int more = (c < SEQL / CHUNK - 1);
        if (more) {
            const float4* src = ebq + (size_t)(c + 1) * CQ;
            p0 = src[to];
            p1 = src[to + 64];
            p2 = src[to + 128];
            p3 = src[to + 192];
            p4 = src[to + 256];
            p5 = src[to + 320];
            if (to < CQ - 384) p6 = src[to + 384];
        }

        for (int s = 0; s < CHUNK; ++s) {
            const int t = c * CHUNK + s;

            float e_nxt = 0.f;
            if (s < CHUNK - 1) e_nxt = ebuf[cb][(s + 1) * CTAGS + toc];
            int m_nxt = (t + 1 < SEQL) ? ml[t + 1] : 0;

            if (to < CTAGS) sb[(size_t)t * CTAGS + to] = cur;

            const float4 s0q  = *(const float4*)&st[0];
            const float4 s1q  = *(const float4*)&st[4];
            const float4 s2q  = *(const float4*)&st[8];
            const float4 s3q  = *(const float4*)&st[12];
            const float4 s4q  = *(const float4*)&st[16];
            const float4 s5q  = *(const float4*)&st[20];
            const float4 s6q  = *(const float4*)&st[24];
            const float4 s7q  = *(const float4*)&st[28];
            const float4 s8q  = *(const float4*)&st[32];
            const float4 s9q  = *(const float4*)&st[36];
            const float4 s10q = *(const float4*)&st[40];
            const float4 s11q = *(const float4*)&st[44];
            const float4 s12q = *(const float4*)&st[48];

            float a[CTAGS];
#define ADQ(q, sq, trq)                                                      \
            a[4*q+0] = sq.x + trq.x;  a[4*q+1] = sq.y + trq.y;               \
            a[4*q+2] = sq.z + trq.z;  a[4*q+3] = sq.w + trq.w;
            ADQ(0, s0q, tr0)   ADQ(1, s1q, tr1)   ADQ(2, s2q, tr2)
            ADQ(3, s3q, tr3)   ADQ(4, s4q, tr4)   ADQ(5, s5q, tr5)
            ADQ(6, s6q, tr6)   ADQ(7, s7q, tr7)   ADQ(8, s8q, tr8)
            ADQ(9, s9q, tr9)   ADQ(10, s10q, tr10) ADQ(11, s11q, tr11)
            ADQ(12, s12q, tr12)
#undef ADQ

            float l1[17];
#pragma unroll
            for (int i = 0; i < 17; ++i)
                l1[i] = fmaxf(fmaxf(a[3 * i], a[3 * i + 1]), a[3 * i + 2]);
            float l2[6];
#pragma unroll
            for (int i = 0; i < 5; ++i)
                l2[i] = fmaxf(fmaxf(l1[3 * i], l1[3 * i + 1]), l1[3 * i + 2]);
            l2[5] = fmaxf(fmaxf(l1[15], l1[16]), a[51]);
            const float m = fmaxf(fmaxf(fmaxf(l2[0], l2[1]), l2[2]),
                                  fmaxf(fmaxf(l2[3], l2[4]), l2[5]));

            cur = m_cur ? (m + e_cur) : cur;

            if (to < CTAGS) st[to] = cur;

            e_cur = e_nxt;
            m_cur = m_nxt;
        }

        if (more) {
            const int nb = cb ^ 1;
            *(float4*)&ebuf[nb][to * 4]         = p0;
            *(float4*)&ebuf[nb][(to + 64) * 4]  = p1;
            *(float4*)&ebuf[nb][(to + 128) * 4] = p2;
            *(float4*)&ebuf[nb][(to + 192) * 4] = p3;
            *(float4*)&ebuf[nb][(to + 256) * 4] = p4;
            *(float4*)&ebuf[nb][(to + 320) * 4] = p5;
            if (to < CQ - 384) *(float4*)&ebuf[nb][(to + 384) * 4] = p6;
            e_cur = ebuf[nb][toc];
        }
        cb ^= 1;
    }

    float v   = (to < CTAGS) ? (cur + tstop) : NEG_INF;
    int  bidx = to;
#pragma unroll
    for (int s = 1; s < 64; s <<= 1) {
        float ov = __shfl_xor(v, s);
        int   oi = __shfl_xor(bidx, s);
        if (ov > v || (ov == v && oi < bidx)) { v = ov; bidx = oi; }
    }
    if (to == 0) { out[b] = v; btag[b] = bidx; }
}

// ---------------------------------------------------------------------------
// K3: backpointers, parallel over (b,t). (unchanged, known-good)
// ---------------------------------------------------------------------------
#define PPW 16

__global__ __launch_bounds__(256) void bp_compute(
    const float* __restrict__ s_hist, const float* __restrict__ T,
    unsigned char* __restrict__ bp)
{
    const int lane = threadIdx.x & 63;
    const int wv   = __builtin_amdgcn_readfirstlane(threadIdx.x >> 6);
    const int toc  = (lane < CTAGS) ? lane : (CTAGS - 1);
    const int w    = blockIdx.x * 4 + wv;

    float Trow[CTAGS];
#pragma unroll
    for (int f = 0; f < CTAGS; ++f) Trow[f] = T[toc * CTAGS + f];

    for (int i = 0; i < PPW; ++i) {
        const int p = w * PPW + i;            // p = b*SEQL + t
        const float* sp = s_hist + (size_t)p * CTAGS;

        float a[CTAGS];
#pragma unroll
        for (int q = 0; q < 13; ++q) {
            float4 sv = *(const float4*)(sp + q * 4);
            a[q * 4 + 0] = sv.x + Trow[q * 4 + 0];
            a[q * 4 + 1] = sv.y + Trow[q * 4 + 1];
            a[q * 4 + 2] = sv.z + Trow[q * 4 + 2];
            a[q * 4 + 3] = sv.w + Trow[q * 4 + 3];
        }

        float l1[17];
#pragma unroll
        for (int j = 0; j < 17; ++j)
            l1[j] = fmaxf(fmaxf(a[3 * j], a[3 * j + 1]), a[3 * j + 2]);
        float l2[6];
#pragma unroll
        for (int j = 0; j < 5; ++j)
            l2[j] = fmaxf(fmaxf(l1[3 * j], l1[3 * j + 1]), l1[3 * j + 2]);
        l2[5] = fmaxf(fmaxf(l1[15], l1[16]), a[51]);
        const float m = fmaxf(fmaxf(fmaxf(l2[0], l2[1]), l2[2]),
                              fmaxf(fmaxf(l2[3], l2[4]), l2[5]));

        int c1[18];
#pragma unroll
        for (int j = 0; j < 17; ++j) {
            int x = (a[3 * j]     == m) ? (3 * j)     : 63;
            int y = (a[3 * j + 1] == m) ? (3 * j + 1) : 63;
            int z = (a[3 * j + 2] == m) ? (3 * j + 2) : 63;
            c1[j] = min(min(x, y), z);
        }
        c1[17] = (a[51] == m) ? 51 : 63;
        int c2[6];
#pragma unroll
        for (int j = 0; j < 6; ++j)
            c2[j] = min(min(c1[3 * j], c1[3 * j + 1]), c1[3 * j + 2]);
        const int idx = min(min(min(c2[0], c2[1]), c2[2]),
                            min(min(c2[3], c2[4]), c2[5]));

        if (lane < CTAGS)
            bp[(size_t)p * CTAGS + lane] = (unsigned char)idx;
    }
}

// ---------------------------------------------------------------------------
// K4: backtrack (unchanged, known-good).
// ---------------------------------------------------------------------------
__global__ __launch_bounds__(64) void viterbi_bt(
    const unsigned char* __restrict__ bp, const int* __restrict__ masks,
    const int* __restrict__ btag, float* __restrict__ out)
{
    const int b   = blockIdx.x;
    const int tid = threadIdx.x;

    __shared__ __align__(16) unsigned char bpl[SEQL * CTAGS];
    __shared__ int ml[SEQL];
    __shared__ unsigned char pathb[SEQL];

    const uint4* src = (const uint4*)(bp + (size_t)b * SEQL * CTAGS);
    for (int i = tid; i < SEQL * CTAGS / 16; i += 64)
        ((uint4*)bpl)[i] = src[i];
    for (int i = tid; i < SEQL; i += 64) ml[i] = masks[(size_t)b * SEQL + i];
    __syncthreads();

    int c = btag[b];
    if (tid == 0) pathb[SEQL - 1] = (unsigned char)c;
    for (int i = SEQL - 2; i >= 0; --i) {
        int nxt = bpl[(i + 1) * CTAGS + c];
        c = ml[i] ? nxt : c;
        if (tid == 0) pathb[i] = (unsigned char)c;
    }
    __syncthreads();

    float* po = out + BATCH + (size_t)b * SEQL;
#pragma unroll
    for (int i = 0; i < 8; ++i)
        po[i * 64 + tid] = (float)pathb[i * 64 + tid];
}

// ---------------------------------------------------------------------------
extern "C" void kernel_launch(void* const* d_in, const int* in_sizes, int n_in,
                              void* d_out, int out_size, void* d_ws, size_t ws_size,
                              hipStream_t stream)
{
    const float* features = (const float*)d_in[0];
    const int*   masks    = (const int*)d_in[1];
    const float* W        = (const float*)d_in[2];
    const float* bias     = (const float*)d_in[3];
    const float* T        = (const float*)d_in[4];

    float* out = (float*)d_out;

    // ws layout: emit/s_hist (13.63 MB, aliased) | bp (3.41 MB) | btag
    // WT (160 KB) aliases the bp region: dead before bp_compute writes.
    const size_t emit_bytes = (size_t)BATCH * SEQL * CTAGS * sizeof(float);
    const size_t bp_bytes   = (size_t)BATCH * SEQL * CTAGS;
    float*         emit   = (float*)d_ws;
    float*         s_hist = emit;  // alias: scan consumes emit[t] before overwrite
    unsigned char* bpws   = (unsigned char*)d_ws + emit_bytes;
    float*         WT     = (float*)bpws;
    int*           btag   = (int*)((unsigned char*)d_ws + emit_bytes + bp_bytes);

    wtrans<<<(FDIM * CTAGS + 255) / 256, 256, 0, stream>>>(W, WT);
    emit_gemm6<<<BATCH * SEQL / 64, 256, 0, stream>>>(features, WT, bias, emit);
    viterbi_scan<<<BATCH, 64, 0, stream>>>(emit, masks, T, s_hist, out, btag);
    bp_compute<<<BATCH * SEQL / (4 * PPW), 256, 0, stream>>>(s_hist, T, bpws);
    viterbi_bt<<<BATCH, 64, 0, stream>>>(bpws, masks, btag, out);
}